// Round 5
// baseline (3155.137 us; speedup 1.0000x reference)
//
#include <hip/hip_runtime.h>
#include <math.h>

#define N_PTS 32768
#define DIM   512
#define K_CL  64
#define ITERS 10
#define EPS_F 1e-8f

// ws layout (floats):
//   ct:     [0, 32768)       transposed centers ct[d*64 + k]
//   sums:   [32768, 65536)   sums[k*512 + d]
//   c2:     [65536, 65600)
//   counts: int32 at float offset 65600
// d_out doubles as per-cluster index lists during iterations.

__global__ void init_centers(const float* __restrict__ x,
                             float* __restrict__ ct,
                             float* __restrict__ c2) {
    int k = blockIdx.x;
    int t = threadIdx.x;
    float ssum = 0.f;
    for (int d = t; d < DIM; d += 256) {
        float v = x[k * DIM + d];
        ct[d * K_CL + k] = v;
        ssum += v * v;
    }
    #pragma unroll
    for (int off = 32; off; off >>= 1) ssum += __shfl_down(ssum, off);
    __shared__ float red[4];
    if ((t & 63) == 0) red[t >> 6] = ssum;
    __syncthreads();
    if (t == 0) c2[k] = red[0] + red[1] + red[2] + red[3];
}

// ---------------------------------------------------------------------------
// 32 pts x 64 cl per 128-thread block (1024 blocks -> 8 waves/CU).
// ct tile (32 dims x 64 cl = 8 KB) DMA'd into STATICALLY double-buffered LDS
// (cs0/cs1 are distinct objects -> no alias-forced vmcnt(0) before ds_reads).
// x rides a 4-deep register pipeline xp[4][4] (slot = q&3, compile-time).
// Per lane: 4 pts x 4 cl, acc[4][4]; ~125 VGPR.
// ---------------------------------------------------------------------------

#define DMA_CT(tt, csX)                                                        \
    {                                                                          \
        _Pragma("unroll")                                                      \
        for (int q_ = 0; q_ < 4; ++q_) {                                       \
            __builtin_amdgcn_global_load_lds(                                  \
                (const __attribute__((address_space(1))) void*)                \
                    (ct + (tt) * 2048 + q_ * 512 + tid * 4),                   \
                (__attribute__((address_space(3))) void*)                      \
                    (&csX[q_ * 512 + tid * 4]),                                \
                16, 0, 0);                                                     \
        }                                                                      \
    }

#define XP(slot, kk)                                                           \
    {                                                                          \
        _Pragma("unroll")                                                      \
        for (int i_ = 0; i_ < 4; ++i_)                                         \
            xp[slot][i_] = *(const float4*)(xb + (size_t)i_ * DIM + (kk) * 4); \
    }

#define LOADC(sl, csX, q)                                                      \
    {                                                                          \
        cvp[sl][0] = *(const float4*)(&csX[((q) * 4 + 0) * 64 + c * 4]);       \
        cvp[sl][1] = *(const float4*)(&csX[((q) * 4 + 1) * 64 + c * 4]);       \
        cvp[sl][2] = *(const float4*)(&csX[((q) * 4 + 2) * 64 + c * 4]);       \
        cvp[sl][3] = *(const float4*)(&csX[((q) * 4 + 3) * 64 + c * 4]);       \
    }

// dims strictly ascending per acc[i][j]: bitwise-identical dots to rounds 1-4
#define QSTEP_DOT(csX, q, kkbase)                                              \
    {                                                                          \
        if ((q) < 7) { LOADC(((q) + 1) & 1, csX, (q) + 1); }                   \
        const float4 cd0 = cvp[(q) & 1][0], cd1 = cvp[(q) & 1][1];             \
        const float4 cd2 = cvp[(q) & 1][2], cd3 = cvp[(q) & 1][3];             \
        _Pragma("unroll")                                                      \
        for (int i = 0; i < 4; ++i) {                                          \
            const float4 xq = xp[(q) & 3][i];                                  \
            acc[i][0] += xq.x * cd0.x; acc[i][1] += xq.x * cd0.y;              \
            acc[i][2] += xq.x * cd0.z; acc[i][3] += xq.x * cd0.w;              \
            acc[i][0] += xq.y * cd1.x; acc[i][1] += xq.y * cd1.y;              \
            acc[i][2] += xq.y * cd1.z; acc[i][3] += xq.y * cd1.w;              \
            acc[i][0] += xq.z * cd2.x; acc[i][1] += xq.z * cd2.y;              \
            acc[i][2] += xq.z * cd2.z; acc[i][3] += xq.z * cd2.w;              \
            acc[i][0] += xq.w * cd3.x; acc[i][1] += xq.w * cd3.y;              \
            acc[i][2] += xq.w * cd3.z; acc[i][3] += xq.w * cd3.w;              \
        }                                                                      \
        if ((kkbase) + (q) + 4 < 128) { XP((q) & 3, (kkbase) + (q) + 4); }     \
    }

#define QSTEP_DIST(csX, q, kkbase)                                             \
    {                                                                          \
        if ((q) < 7) { LOADC(((q) + 1) & 1, csX, (q) + 1); }                   \
        const float4 cd0 = cvp[(q) & 1][0], cd1 = cvp[(q) & 1][1];             \
        const float4 cd2 = cvp[(q) & 1][2], cd3 = cvp[(q) & 1][3];             \
        _Pragma("unroll")                                                      \
        for (int i = 0; i < 4; ++i) {                                          \
            const float4 xq = xp[(q) & 3][i];                                  \
            float d0, d1, d2, d3;                                              \
            d0 = xq.x - cd0.x; acc[i][0] += d0 * d0;                           \
            d1 = xq.x - cd0.y; acc[i][1] += d1 * d1;                           \
            d2 = xq.x - cd0.z; acc[i][2] += d2 * d2;                           \
            d3 = xq.x - cd0.w; acc[i][3] += d3 * d3;                           \
            d0 = xq.y - cd1.x; acc[i][0] += d0 * d0;                           \
            d1 = xq.y - cd1.y; acc[i][1] += d1 * d1;                           \
            d2 = xq.y - cd1.z; acc[i][2] += d2 * d2;                           \
            d3 = xq.y - cd1.w; acc[i][3] += d3 * d3;                           \
            d0 = xq.z - cd2.x; acc[i][0] += d0 * d0;                           \
            d1 = xq.z - cd2.y; acc[i][1] += d1 * d1;                           \
            d2 = xq.z - cd2.z; acc[i][2] += d2 * d2;                           \
            d3 = xq.z - cd2.w; acc[i][3] += d3 * d3;                           \
            d0 = xq.w - cd3.x; acc[i][0] += d0 * d0;                           \
            d1 = xq.w - cd3.y; acc[i][1] += d1 * d1;                           \
            d2 = xq.w - cd3.z; acc[i][2] += d2 * d2;                           \
            d3 = xq.w - cd3.w; acc[i][3] += d3 * d3;                           \
        }                                                                      \
        if ((kkbase) + (q) + 4 < 128) { XP((q) & 3, (kkbase) + (q) + 4); }     \
    }

#define TILE(BODY, csX, kkbase)                                                \
    {                                                                          \
        LOADC(0, csX, 0);                                                      \
        BODY(csX, 0, kkbase); BODY(csX, 1, kkbase);                            \
        BODY(csX, 2, kkbase); BODY(csX, 3, kkbase);                            \
        BODY(csX, 4, kkbase); BODY(csX, 5, kkbase);                            \
        BODY(csX, 6, kkbase); BODY(csX, 7, kkbase);                            \
    }

__launch_bounds__(128)
__global__ void assign_scatter(const float* __restrict__ x,
                               const float* __restrict__ ct,
                               const float* __restrict__ c2,
                               int* __restrict__ counts,
                               int* __restrict__ lists) {
    __shared__ float cs0[2048];
    __shared__ float cs1[2048];
    __shared__ float c2s[K_CL];

    const int tid = threadIdx.x;
    const int pbase = blockIdx.x * 32;
    const int rr = tid >> 4;   // 0..7: point group (4 pts)
    const int c  = tid & 15;   // cluster quad
    if (tid < K_CL) c2s[tid] = c2[tid];

    const float* xb = x + (size_t)(pbase + rr * 4) * DIM;

    float4 xp[4][4];
    float4 cvp[2][4];
    float acc[4][4] = {};

    DMA_CT(0, cs0);
    XP(0, 0); XP(1, 1); XP(2, 2); XP(3, 3);
    __syncthreads();

    for (int tt = 0; tt < 16; tt += 2) {
        if (tt + 1 < 16) DMA_CT(tt + 1, cs1);
        TILE(QSTEP_DOT, cs0, tt * 8);
        __syncthreads();
        if (tt + 2 < 16) DMA_CT(tt + 2, cs0);
        TILE(QSTEP_DOT, cs1, (tt + 1) * 8);
        __syncthreads();
    }

    #pragma unroll
    for (int i = 0; i < 4; ++i) {
        float bv = 1e30f; int bc = 0;
        #pragma unroll
        for (int j = 0; j < 4; ++j) {
            float v = c2s[c * 4 + j] - 2.0f * acc[i][j];
            if (v < bv) { bv = v; bc = c * 4 + j; }
        }
        #pragma unroll
        for (int m = 1; m < 16; m <<= 1) {
            float ov = __shfl_xor(bv, m);
            int   oc = __shfl_xor(bc, m);
            if (ov < bv || (ov == bv && oc < bc)) { bv = ov; bc = oc; }
        }
        if (c == 0) {
            int p = pbase + rr * 4 + i;
            int slot = atomicAdd(&counts[bc], 1);
            lists[bc * N_PTS + slot] = p;
        }
    }
}

__global__ void gather_sums(const float* __restrict__ x,
                            const int* __restrict__ lists,
                            const int* __restrict__ counts,
                            float* __restrict__ sums) {
    int k  = blockIdx.x;
    int dc = blockIdx.y;
    int pc = blockIdx.z;
    int t  = threadIdx.x;
    int n  = counts[k];
    int s0 = (n * pc) >> 3;
    int s1 = (n * (pc + 1)) >> 3;
    int d  = dc * 128 + t;
    const int* lst = lists + k * N_PTS;
    float acc = 0.f;
    int s = s0;
    for (; s + 8 <= s1; s += 8) {
        int idx[8];
        #pragma unroll
        for (int q = 0; q < 8; ++q) idx[q] = lst[s + q];
        #pragma unroll
        for (int q = 0; q < 8; ++q) acc += x[(size_t)idx[q] * DIM + d];
    }
    for (; s < s1; ++s) acc += x[(size_t)lst[s] * DIM + d];
    atomicAdd(&sums[k * DIM + d], acc);
}

__global__ void update_centers(float* __restrict__ ct,
                               const float* __restrict__ sums,
                               const int* __restrict__ counts,
                               float* __restrict__ c2) {
    int k = blockIdx.x;
    int t = threadIdx.x;
    int cnt = counts[k];
    float fc = (float)cnt;
    float ssum = 0.f;
    for (int d = t; d < DIM; d += 256) {
        float v = ct[d * K_CL + k];
        if (cnt > 0) v = sums[k * DIM + d] / fc;
        ct[d * K_CL + k] = v;
        ssum += v * v;
    }
    #pragma unroll
    for (int off = 32; off; off >>= 1) ssum += __shfl_down(ssum, off);
    __shared__ float red[4];
    if ((t & 63) == 0) red[t >> 6] = ssum;
    __syncthreads();
    if (t == 0) c2[k] = red[0] + red[1] + red[2] + red[3];
}

// Final distances via direct differencing (exact 0 at singletons).
__launch_bounds__(128)
__global__ void final_dist(const float* __restrict__ x,
                           const float* __restrict__ ct,
                           float* __restrict__ out) {
    __shared__ float cs0[2048];
    __shared__ float cs1[2048];

    const int tid = threadIdx.x;
    const int pbase = blockIdx.x * 32;
    const int rr = tid >> 4;
    const int c  = tid & 15;

    const float* xb = x + (size_t)(pbase + rr * 4) * DIM;

    float4 xp[4][4];
    float4 cvp[2][4];
    float acc[4][4] = {};

    DMA_CT(0, cs0);
    XP(0, 0); XP(1, 1); XP(2, 2); XP(3, 3);
    __syncthreads();

    for (int tt = 0; tt < 16; tt += 2) {
        if (tt + 1 < 16) DMA_CT(tt + 1, cs1);
        TILE(QSTEP_DIST, cs0, tt * 8);
        __syncthreads();
        if (tt + 2 < 16) DMA_CT(tt + 2, cs0);
        TILE(QSTEP_DIST, cs1, (tt + 1) * 8);
        __syncthreads();
    }

    #pragma unroll
    for (int i = 0; i < 4; ++i) {
        int p = pbase + rr * 4 + i;
        float4 o;
        o.x = 1.0f / (sqrtf(acc[i][0]) + EPS_F);
        o.y = 1.0f / (sqrtf(acc[i][1]) + EPS_F);
        o.z = 1.0f / (sqrtf(acc[i][2]) + EPS_F);
        o.w = 1.0f / (sqrtf(acc[i][3]) + EPS_F);
        *(float4*)(out + (size_t)p * K_CL + c * 4) = o;
    }
}

extern "C" void kernel_launch(void* const* d_in, const int* in_sizes, int n_in,
                              void* d_out, int out_size, void* d_ws, size_t ws_size,
                              hipStream_t stream) {
    (void)in_sizes; (void)n_in; (void)out_size; (void)ws_size;
    const float* x = (const float*)d_in[0];
    float* ws      = (float*)d_ws;
    float* ct      = ws;
    float* sums    = ws + 32768;
    float* c2      = ws + 65536;
    int*   counts  = (int*)(ws + 65600);
    int*   lists   = (int*)d_out;
    float* out     = (float*)d_out;

    init_centers<<<64, 256, 0, stream>>>(x, ct, c2);
    for (int it = 0; it < ITERS; ++it) {
        hipMemsetAsync(counts, 0, K_CL * sizeof(int), stream);
        hipMemsetAsync(sums, 0, K_CL * DIM * sizeof(float), stream);
        assign_scatter<<<1024, 128, 0, stream>>>(x, ct, c2, counts, lists);
        gather_sums<<<dim3(64, 4, 8), 128, 0, stream>>>(x, lists, counts, sums);
        update_centers<<<64, 256, 0, stream>>>(ct, sums, counts, c2);
    }
    final_dist<<<1024, 128, 0, stream>>>(x, ct, out);
}

// Round 6
// 1863.368 us; speedup vs baseline: 1.6932x; 1.6932x over previous
//
#include <hip/hip_runtime.h>
#include <math.h>

#define N_PTS 32768
#define DIM   512
#define K_CL  64
#define ITERS 10
#define EPS_F 1e-8f

typedef __attribute__((ext_vector_type(8))) short          short8v;
typedef __attribute__((ext_vector_type(8))) unsigned short ushort8v;
typedef __attribute__((ext_vector_type(4))) float          f32x4v;

__device__ __forceinline__ unsigned short f2bf(float f) {
    unsigned u = __builtin_bit_cast(unsigned, f);
    unsigned r = u + 0x7fffu + ((u >> 16) & 1u);
    return (unsigned short)(r >> 16);
}
__device__ __forceinline__ float bf2f(unsigned short h) {
    return __builtin_bit_cast(float, ((unsigned)h) << 16);
}

// ws layout (floats):
//   ct:     [0, 32768)        transposed fp32 centers ct[d*64 + k] (final_dist)
//   sums:   [32768, 65536)    sums[k*512 + d]
//   c2:     [65536, 65600)
//   counts: int32 at float offset 65600 (64 ints)
//   cth:    ushort at float offset 65664  (64x512 bf16-hi, row-major [k][d])
//   ctl:    ushort at float offset 82048  (64x512 bf16-lo)
// d_out doubles as per-cluster index lists during iterations.

__global__ void init_centers(const float* __restrict__ x,
                             float* __restrict__ ct,
                             float* __restrict__ c2,
                             unsigned short* __restrict__ cth,
                             unsigned short* __restrict__ ctl) {
    int k = blockIdx.x;
    int t = threadIdx.x;
    float ssum = 0.f;
    for (int d = t; d < DIM; d += 256) {
        float v = x[k * DIM + d];
        ct[d * K_CL + k] = v;
        unsigned short h = f2bf(v);
        cth[k * DIM + d] = h;
        ctl[k * DIM + d] = f2bf(v - bf2f(h));
        ssum += v * v;
    }
    #pragma unroll
    for (int off = 32; off; off >>= 1) ssum += __shfl_down(ssum, off);
    __shared__ float red[4];
    if ((t & 63) == 0) red[t >> 6] = ssum;
    __syncthreads();
    if (t == 0) c2[k] = red[0] + red[1] + red[2] + red[3];
}

// ---------------------------------------------------------------------------
// MFMA assignment: one wave per 32 points, no LDS, no barriers.
// dot = xh*ch + xh*cl + xl*ch  (bf16 split, error ~1e-3 on d2; argmin-safe).
// A-frag: x row (lane&15), k = (lane>>4)*8+j   (converted fp32->bf16 hi/lo)
// B-frag: ct row (lane&15 = cluster), same k pattern (row-major cth/ctl).
// C/D:    col = lane&15 (cluster), row = (lane>>4)*4 + reg.
// ---------------------------------------------------------------------------
__launch_bounds__(64)
__global__ void assign_mfma(const float* __restrict__ x,
                            const unsigned short* __restrict__ cth,
                            const unsigned short* __restrict__ ctl,
                            const float* __restrict__ c2,
                            int* __restrict__ counts,
                            int* __restrict__ lists) {
    const int lane  = threadIdx.x;
    const int mbase = blockIdx.x * 32;
    const int mrow  = lane & 15;
    const int kgrp  = lane >> 4;

    const float* xr0 = x + (size_t)(mbase + mrow) * DIM + kgrp * 8;
    const float* xr1 = x + (size_t)(mbase + 16 + mrow) * DIM + kgrp * 8;
    const unsigned short* cb = (const unsigned short*)0;

    f32x4v acc[2][4];
    #pragma unroll
    for (int mt = 0; mt < 2; ++mt)
        #pragma unroll
        for (int nt = 0; nt < 4; ++nt)
            acc[mt][nt] = (f32x4v){0.f, 0.f, 0.f, 0.f};

    float4 xraw[2][2][2];   // [buf][mt][half]
    xraw[0][0][0] = *(const float4*)(xr0);
    xraw[0][0][1] = *(const float4*)(xr0 + 4);
    xraw[0][1][0] = *(const float4*)(xr1);
    xraw[0][1][1] = *(const float4*)(xr1 + 4);

    int buf = 0;
    for (int ks = 0; ks < 16; ++ks) {
        if (ks < 15) {
            const int kb = (ks + 1) * 32;
            xraw[buf ^ 1][0][0] = *(const float4*)(xr0 + kb);
            xraw[buf ^ 1][0][1] = *(const float4*)(xr0 + kb + 4);
            xraw[buf ^ 1][1][0] = *(const float4*)(xr1 + kb);
            xraw[buf ^ 1][1][1] = *(const float4*)(xr1 + kb + 4);
        }
        // B fragments for this k-step (L2-resident, 128 KB total)
        short8v bh[4], bl[4];
        const int kb = ks * 32 + kgrp * 8;
        #pragma unroll
        for (int nt = 0; nt < 4; ++nt) {
            const size_t off = (size_t)(nt * 16 + mrow) * DIM + kb;
            bh[nt] = *(const short8v*)(cth + off);
            bl[nt] = *(const short8v*)(ctl + off);
        }
        // convert current x chunk to bf16 hi/lo fragments
        short8v ah[2], al[2];
        #pragma unroll
        for (int mt = 0; mt < 2; ++mt) {
            float fs[8] = {xraw[buf][mt][0].x, xraw[buf][mt][0].y,
                           xraw[buf][mt][0].z, xraw[buf][mt][0].w,
                           xraw[buf][mt][1].x, xraw[buf][mt][1].y,
                           xraw[buf][mt][1].z, xraw[buf][mt][1].w};
            ushort8v h, l;
            #pragma unroll
            for (int i = 0; i < 8; ++i) {
                unsigned short hh = f2bf(fs[i]);
                h[i] = hh;
                l[i] = f2bf(fs[i] - bf2f(hh));
            }
            ah[mt] = __builtin_bit_cast(short8v, h);
            al[mt] = __builtin_bit_cast(short8v, l);
        }
        #pragma unroll
        for (int mt = 0; mt < 2; ++mt)
            #pragma unroll
            for (int nt = 0; nt < 4; ++nt) {
                acc[mt][nt] = __builtin_amdgcn_mfma_f32_16x16x32_bf16(
                    ah[mt], bh[nt], acc[mt][nt], 0, 0, 0);
                acc[mt][nt] = __builtin_amdgcn_mfma_f32_16x16x32_bf16(
                    ah[mt], bl[nt], acc[mt][nt], 0, 0, 0);
                acc[mt][nt] = __builtin_amdgcn_mfma_f32_16x16x32_bf16(
                    al[mt], bh[nt], acc[mt][nt], 0, 0, 0);
            }
        buf ^= 1;
    }
    (void)cb;

    float c2v[4];
    #pragma unroll
    for (int nt = 0; nt < 4; ++nt) c2v[nt] = c2[nt * 16 + mrow];

    #pragma unroll
    for (int mt = 0; mt < 2; ++mt)
        #pragma unroll
        for (int r = 0; r < 4; ++r) {
            float bv = 1e30f; int bc = 0;
            #pragma unroll
            for (int nt = 0; nt < 4; ++nt) {
                float v = c2v[nt] - 2.0f * acc[mt][nt][r];
                if (v < bv) { bv = v; bc = nt * 16 + mrow; }
            }
            #pragma unroll
            for (int m = 1; m < 16; m <<= 1) {
                float ov = __shfl_xor(bv, m);
                int   oc = __shfl_xor(bc, m);
                if (ov < bv || (ov == bv && oc < bc)) { bv = ov; bc = oc; }
            }
            if (mrow == 0) {
                int p = mbase + mt * 16 + kgrp * 4 + r;
                int slot = atomicAdd(&counts[bc], 1);
                lists[bc * N_PTS + slot] = p;
            }
        }
}

__global__ void gather_sums(const float* __restrict__ x,
                            const int* __restrict__ lists,
                            const int* __restrict__ counts,
                            float* __restrict__ sums) {
    int k  = blockIdx.x;
    int dc = blockIdx.y;
    int pc = blockIdx.z;
    int t  = threadIdx.x;
    int n  = counts[k];
    int s0 = (n * pc) >> 3;
    int s1 = (n * (pc + 1)) >> 3;
    int d  = dc * 128 + t;
    const int* lst = lists + k * N_PTS;
    float acc = 0.f;
    int s = s0;
    for (; s + 8 <= s1; s += 8) {
        int idx[8];
        #pragma unroll
        for (int q = 0; q < 8; ++q) idx[q] = lst[s + q];
        #pragma unroll
        for (int q = 0; q < 8; ++q) acc += x[(size_t)idx[q] * DIM + d];
    }
    for (; s < s1; ++s) acc += x[(size_t)lst[s] * DIM + d];
    atomicAdd(&sums[k * DIM + d], acc);
}

__global__ void update_centers(float* __restrict__ ct,
                               const float* __restrict__ sums,
                               const int* __restrict__ counts,
                               float* __restrict__ c2,
                               unsigned short* __restrict__ cth,
                               unsigned short* __restrict__ ctl) {
    int k = blockIdx.x;
    int t = threadIdx.x;
    int cnt = counts[k];
    float fc = (float)cnt;
    float ssum = 0.f;
    for (int d = t; d < DIM; d += 256) {
        float v = ct[d * K_CL + k];
        if (cnt > 0) v = sums[k * DIM + d] / fc;
        ct[d * K_CL + k] = v;
        unsigned short h = f2bf(v);
        cth[k * DIM + d] = h;
        ctl[k * DIM + d] = f2bf(v - bf2f(h));
        ssum += v * v;
    }
    #pragma unroll
    for (int off = 32; off; off >>= 1) ssum += __shfl_down(ssum, off);
    __shared__ float red[4];
    if ((t & 63) == 0) red[t >> 6] = ssum;
    __syncthreads();
    if (t == 0) c2[k] = red[0] + red[1] + red[2] + red[3];
}

// ---------------------------------------------------------------------------
// Final distances via direct fp32 differencing (exact 0 at singletons).
// Same structure as the passing round-4 kernel.
// ---------------------------------------------------------------------------
#define DMA_T(tt, bb)                                                          \
    {                                                                          \
        _Pragma("unroll")                                                      \
        for (int q_ = 0; q_ < 4; ++q_) {                                       \
            __builtin_amdgcn_global_load_lds(                                  \
                (const __attribute__((address_space(1))) void*)                \
                    (ct + (tt) * 2048 + q_ * 512 + tid * 4),                   \
                (__attribute__((address_space(3))) void*)                      \
                    (&cs[bb][q_ * 512 + tid * 4]),                             \
                16, 0, 0);                                                     \
        }                                                                      \
        _Pragma("unroll")                                                      \
        for (int q_ = 0; q_ < 4; ++q_) {                                       \
            const int s_ = q_ * 128 + tid;                                     \
            __builtin_amdgcn_global_load_lds(                                  \
                (const __attribute__((address_space(1))) void*)                \
                    (x + (size_t)(pbase + (s_ >> 3)) * DIM +                   \
                     (tt) * 32 + (s_ & 7) * 4),                                \
                (__attribute__((address_space(3))) void*)                      \
                    (&xs[bb][s_ * 4]),                                         \
                16, 0, 0);                                                     \
        }                                                                      \
    }

#define LOADX(sl, kq)                                                          \
    {                                                                          \
        _Pragma("unroll")                                                      \
        for (int i_ = 0; i_ < 8; ++i_)                                         \
            xv[sl][i_] = *(const float4*)(&xs[buf][(rr * 8 + i_) * 32 +        \
                                                   (kq) * 4]);                 \
    }

#define LOADC(sl, kq)                                                          \
    {                                                                          \
        _Pragma("unroll")                                                      \
        for (int j_ = 0; j_ < 4; ++j_)                                         \
            cv[sl][j_] = *(const float4*)(&cs[buf][((kq) * 4 + j_) * 64 +      \
                                                   c * 4]);                    \
    }

#define BODY_DIST(kq)                                                          \
    {                                                                          \
        if ((kq) < 7) { LOADX(((kq) + 1) & 1, (kq) + 1);                       \
                        LOADC(((kq) + 1) & 1, (kq) + 1); }                     \
        const float4 c0 = cv[(kq) & 1][0], c1 = cv[(kq) & 1][1];               \
        const float4 c2v = cv[(kq) & 1][2], c3 = cv[(kq) & 1][3];              \
        _Pragma("unroll")                                                      \
        for (int i = 0; i < 8; ++i) {                                          \
            const float4 xq = xv[(kq) & 1][i];                                 \
            float d0, d1, d2, d3;                                              \
            d0 = xq.x - c0.x;  acc[i][0] += d0 * d0;                           \
            d1 = xq.x - c0.y;  acc[i][1] += d1 * d1;                           \
            d2 = xq.x - c0.z;  acc[i][2] += d2 * d2;                           \
            d3 = xq.x - c0.w;  acc[i][3] += d3 * d3;                           \
            d0 = xq.y - c1.x;  acc[i][0] += d0 * d0;                           \
            d1 = xq.y - c1.y;  acc[i][1] += d1 * d1;                           \
            d2 = xq.y - c1.z;  acc[i][2] += d2 * d2;                           \
            d3 = xq.y - c1.w;  acc[i][3] += d3 * d3;                           \
            d0 = xq.z - c2v.x; acc[i][0] += d0 * d0;                           \
            d1 = xq.z - c2v.y; acc[i][1] += d1 * d1;                           \
            d2 = xq.z - c2v.z; acc[i][2] += d2 * d2;                           \
            d3 = xq.z - c2v.w; acc[i][3] += d3 * d3;                           \
            d0 = xq.w - c3.x;  acc[i][0] += d0 * d0;                           \
            d1 = xq.w - c3.y;  acc[i][1] += d1 * d1;                           \
            d2 = xq.w - c3.z;  acc[i][2] += d2 * d2;                           \
            d3 = xq.w - c3.w;  acc[i][3] += d3 * d3;                           \
        }                                                                      \
    }

__launch_bounds__(128)
__global__ void final_dist(const float* __restrict__ x,
                           const float* __restrict__ ct,
                           float* __restrict__ out) {
    __shared__ float xs[2][2048];
    __shared__ float cs[2][2048];

    const int tid = threadIdx.x;
    const int pbase = blockIdx.x * 64;
    const int rr = tid >> 4;
    const int c  = tid & 15;

    float4 xv[2][8];
    float4 cv[2][4];
    float acc[8][4] = {};

    DMA_T(0, 0);
    __syncthreads();

    int buf = 0;
    for (int t = 0; t < 16; ++t) {
        if (t < 15) DMA_T(t + 1, buf ^ 1);
        LOADX(0, 0); LOADC(0, 0);
        BODY_DIST(0); BODY_DIST(1); BODY_DIST(2); BODY_DIST(3);
        BODY_DIST(4); BODY_DIST(5); BODY_DIST(6); BODY_DIST(7);
        __syncthreads();
        buf ^= 1;
    }

    #pragma unroll
    for (int i = 0; i < 8; ++i) {
        int p = pbase + rr * 8 + i;
        float4 o;
        o.x = 1.0f / (sqrtf(acc[i][0]) + EPS_F);
        o.y = 1.0f / (sqrtf(acc[i][1]) + EPS_F);
        o.z = 1.0f / (sqrtf(acc[i][2]) + EPS_F);
        o.w = 1.0f / (sqrtf(acc[i][3]) + EPS_F);
        *(float4*)(out + (size_t)p * K_CL + c * 4) = o;
    }
}

extern "C" void kernel_launch(void* const* d_in, const int* in_sizes, int n_in,
                              void* d_out, int out_size, void* d_ws, size_t ws_size,
                              hipStream_t stream) {
    (void)in_sizes; (void)n_in; (void)out_size; (void)ws_size;
    const float* x = (const float*)d_in[0];
    float* ws      = (float*)d_ws;
    float* ct      = ws;
    float* sums    = ws + 32768;
    float* c2      = ws + 65536;
    int*   counts  = (int*)(ws + 65600);
    unsigned short* cth = (unsigned short*)(ws + 65664);
    unsigned short* ctl = (unsigned short*)(ws + 82048);
    int*   lists   = (int*)d_out;
    float* out     = (float*)d_out;

    init_centers<<<64, 256, 0, stream>>>(x, ct, c2, cth, ctl);
    for (int it = 0; it < ITERS; ++it) {
        hipMemsetAsync(counts, 0, K_CL * sizeof(int), stream);
        hipMemsetAsync(sums, 0, K_CL * DIM * sizeof(float), stream);
        assign_mfma<<<1024, 64, 0, stream>>>(x, cth, ctl, c2, counts, lists);
        gather_sums<<<dim3(64, 4, 8), 128, 0, stream>>>(x, lists, counts, sums);
        update_centers<<<64, 256, 0, stream>>>(ct, sums, counts, c2, cth, ctl);
    }
    final_dist<<<512, 128, 0, stream>>>(x, ct, out);
}

// Round 8
// 1648.019 us; speedup vs baseline: 1.9145x; 1.1307x over previous
//
#include <hip/hip_runtime.h>
#include <math.h>

#define N_PTS 32768
#define DIM   512
#define K_CL  64
#define ITERS 10
#define EPS_F 1e-8f

typedef __attribute__((ext_vector_type(8))) short          short8v;
typedef __attribute__((ext_vector_type(8))) unsigned short ushort8v;
typedef __attribute__((ext_vector_type(4))) float          f32x4v;

__device__ __forceinline__ unsigned short f2bf(float f) {
    unsigned u = __builtin_bit_cast(unsigned, f);
    unsigned r = u + 0x7fffu + ((u >> 16) & 1u);
    return (unsigned short)(r >> 16);
}
__device__ __forceinline__ float bf2f(unsigned short h) {
    return __builtin_bit_cast(float, ((unsigned)h) << 16);
}

// ws layout (floats):
//   ct:      [0, 32768)       fp32 centers transposed ct[d*64+k] (final_dist)
//   sums:    [32768, 65536)   combined sums[k*512+d]
//   c2:      [65536, 65600)
//   cth:     ushort @ float 65600  (64x512 bf16-hi, row-major)
//   ctl:     ushort @ float 81984  (64x512 bf16-lo)
//   rcnt:    int    @ float 98368  (64 clusters x 8 regions)
//   assignv: int    @ float 98880  (32768)
// d_out holds per-cluster region lists during iterations:
//   lists[k*32768 + pc*4096 + i], region pc covers points [pc*4096,(pc+1)*4096)

__global__ void init_centers(const float* __restrict__ x,
                             float* __restrict__ ct,
                             float* __restrict__ c2,
                             unsigned short* __restrict__ cth,
                             unsigned short* __restrict__ ctl) {
    int k = blockIdx.x;
    int t = threadIdx.x;
    float ssum = 0.f;
    for (int d = t; d < DIM; d += 256) {
        float v = x[k * DIM + d];
        ct[d * K_CL + k] = v;
        unsigned short h = f2bf(v);
        cth[k * DIM + d] = h;
        ctl[k * DIM + d] = f2bf(v - bf2f(h));
        ssum += v * v;
    }
    #pragma unroll
    for (int off = 32; off; off >>= 1) ssum += __shfl_down(ssum, off);
    __shared__ float red[4];
    if ((t & 63) == 0) red[t >> 6] = ssum;
    __syncthreads();
    if (t == 0) c2[k] = red[0] + red[1] + red[2] + red[3];
}

// ---------------------------------------------------------------------------
// MFMA assignment, one wave per 16 points. dot = xh*ch + xh*cl + xl*ch
// (bf16 split; per-point MFMA sequence bitwise-identical to round 6).
// Writes assign[p] only — NO atomics, fully deterministic.
// ---------------------------------------------------------------------------
__launch_bounds__(64)
__global__ void assign_mfma(const float* __restrict__ x,
                            const unsigned short* __restrict__ cth,
                            const unsigned short* __restrict__ ctl,
                            const float* __restrict__ c2,
                            int* __restrict__ assignv) {
    const int lane  = threadIdx.x;
    const int mbase = blockIdx.x * 16;
    const int mrow  = lane & 15;
    const int kgrp  = lane >> 4;

    const float* xr = x + (size_t)(mbase + mrow) * DIM + kgrp * 8;
    const unsigned short* cbh = cth + (size_t)mrow * DIM + kgrp * 8;
    const unsigned short* cbl = ctl + (size_t)mrow * DIM + kgrp * 8;

    f32x4v acc[4];
    acc[0] = acc[1] = acc[2] = acc[3] = (f32x4v){0.f, 0.f, 0.f, 0.f};

    float4 xraw[2][2];
    xraw[0][0] = *(const float4*)(xr);
    xraw[0][1] = *(const float4*)(xr + 4);

    int buf = 0;
    for (int ks = 0; ks < 16; ++ks) {
        if (ks < 15) {
            xraw[buf ^ 1][0] = *(const float4*)(xr + (ks + 1) * 32);
            xraw[buf ^ 1][1] = *(const float4*)(xr + (ks + 1) * 32 + 4);
        }
        short8v bh[4], bl[4];
        #pragma unroll
        for (int nt = 0; nt < 4; ++nt) {
            const size_t off = (size_t)nt * 16 * DIM + ks * 32;
            bh[nt] = *(const short8v*)(cbh + off);
            bl[nt] = *(const short8v*)(cbl + off);
        }
        short8v ah, al;
        {
            float fs[8] = {xraw[buf][0].x, xraw[buf][0].y,
                           xraw[buf][0].z, xraw[buf][0].w,
                           xraw[buf][1].x, xraw[buf][1].y,
                           xraw[buf][1].z, xraw[buf][1].w};
            ushort8v h, l;
            #pragma unroll
            for (int i = 0; i < 8; ++i) {
                unsigned short hh = f2bf(fs[i]);
                h[i] = hh;
                l[i] = f2bf(fs[i] - bf2f(hh));
            }
            ah = __builtin_bit_cast(short8v, h);
            al = __builtin_bit_cast(short8v, l);
        }
        #pragma unroll
        for (int nt = 0; nt < 4; ++nt) {
            acc[nt] = __builtin_amdgcn_mfma_f32_16x16x32_bf16(
                ah, bh[nt], acc[nt], 0, 0, 0);
            acc[nt] = __builtin_amdgcn_mfma_f32_16x16x32_bf16(
                ah, bl[nt], acc[nt], 0, 0, 0);
            acc[nt] = __builtin_amdgcn_mfma_f32_16x16x32_bf16(
                al, bh[nt], acc[nt], 0, 0, 0);
        }
        buf ^= 1;
    }

    float c2v[4];
    #pragma unroll
    for (int nt = 0; nt < 4; ++nt) c2v[nt] = c2[nt * 16 + mrow];

    #pragma unroll
    for (int r = 0; r < 4; ++r) {
        float bv = 1e30f; int bc = 0;
        #pragma unroll
        for (int nt = 0; nt < 4; ++nt) {
            float v = c2v[nt] - 2.0f * acc[nt][r];
            if (v < bv) { bv = v; bc = nt * 16 + mrow; }
        }
        #pragma unroll
        for (int m = 1; m < 16; m <<= 1) {
            float ov = __shfl_xor(bv, m);
            int   oc = __shfl_xor(bc, m);
            if (ov < bv || (ov == bv && oc < bc)) { bv = ov; bc = oc; }
        }
        if (mrow == 0) assignv[mbase + kgrp * 4 + r] = bc;
    }
}

// Ordered wave-ballot compaction: cluster k, region pc (4096 points) ->
// members in strictly ascending point order. Fully deterministic.
__launch_bounds__(64)
__global__ void build_lists(const int* __restrict__ assignv,
                            int* __restrict__ lists,
                            int* __restrict__ rcnt) {
    const int k    = blockIdx.x;
    const int pc   = blockIdx.y;
    const int lane = threadIdx.x;
    const int p0   = pc * 4096;
    int* dst = lists + k * N_PTS + pc * 4096;

    int base = 0;
    int a_cur = assignv[p0 + lane];
    for (int it = 0; it < 64; ++it) {
        int a_nxt = 0;
        if (it < 63) a_nxt = assignv[p0 + (it + 1) * 64 + lane];
        bool pred = (a_cur == k);
        unsigned long long mask = __ballot(pred);
        int myoff = __popcll(mask & ((1ull << lane) - 1ull));
        if (pred) dst[base + myoff] = p0 + it * 64 + lane;
        base += __popcll(mask);
        a_cur = a_nxt;
    }
    if (lane == 0) rcnt[k * 8 + pc] = base;
}

// Deterministic gather: regions pc=0..7 in order, members in list order,
// fp32 adds in fixed sequence. No atomics.
__global__ void gather_det(const float* __restrict__ x,
                           const int* __restrict__ lists,
                           const int* __restrict__ rcnt,
                           float* __restrict__ sums) {
    const int k  = blockIdx.x;
    const int dc = blockIdx.y;
    const int t  = threadIdx.x;
    const int d  = dc * 128 + t;
    float acc = 0.f;
    #pragma unroll 1
    for (int pc = 0; pc < 8; ++pc) {
        const int n = rcnt[k * 8 + pc];
        const int* lst = lists + k * N_PTS + pc * 4096;
        int s = 0;
        for (; s + 8 <= n; s += 8) {
            int idx[8];
            #pragma unroll
            for (int q = 0; q < 8; ++q) idx[q] = lst[s + q];
            #pragma unroll
            for (int q = 0; q < 8; ++q) acc += x[(size_t)idx[q] * DIM + d];
        }
        for (; s < n; ++s) acc += x[(size_t)lst[s] * DIM + d];
    }
    sums[k * DIM + d] = acc;
}

__global__ void update_centers(float* __restrict__ ct,
                               const float* __restrict__ sums,
                               const int* __restrict__ rcnt,
                               float* __restrict__ c2,
                               unsigned short* __restrict__ cth,
                               unsigned short* __restrict__ ctl) {
    int k = blockIdx.x;
    int t = threadIdx.x;
    int cnt = 0;
    #pragma unroll
    for (int pc = 0; pc < 8; ++pc) cnt += rcnt[k * 8 + pc];
    float fc = (float)cnt;
    float ssum = 0.f;
    for (int d = t; d < DIM; d += 256) {
        float v = ct[d * K_CL + k];
        if (cnt > 0) v = sums[k * DIM + d] / fc;
        ct[d * K_CL + k] = v;
        unsigned short h = f2bf(v);
        cth[k * DIM + d] = h;
        ctl[k * DIM + d] = f2bf(v - bf2f(h));
        ssum += v * v;
    }
    #pragma unroll
    for (int off = 32; off; off >>= 1) ssum += __shfl_down(ssum, off);
    __shared__ float red[4];
    if ((t & 63) == 0) red[t >> 6] = ssum;
    __syncthreads();
    if (t == 0) c2[k] = red[0] + red[1] + red[2] + red[3];
}

// ---------------------------------------------------------------------------
// Final distances via exact fp32 differencing (round-6 kernel, known-pass):
// d2 == 0 bitwise at any point equal to its center -> exact 1e8 entries.
// ---------------------------------------------------------------------------
#define DMA_T(tt, bb)                                                          \
    {                                                                          \
        _Pragma("unroll")                                                      \
        for (int q_ = 0; q_ < 4; ++q_) {                                       \
            __builtin_amdgcn_global_load_lds(                                  \
                (const __attribute__((address_space(1))) void*)                \
                    (ct + (tt) * 2048 + q_ * 512 + tid * 4),                   \
                (__attribute__((address_space(3))) void*)                      \
                    (&cs[bb][q_ * 512 + tid * 4]),                             \
                16, 0, 0);                                                     \
        }                                                                      \
        _Pragma("unroll")                                                      \
        for (int q_ = 0; q_ < 4; ++q_) {                                       \
            const int s_ = q_ * 128 + tid;                                     \
            __builtin_amdgcn_global_load_lds(                                  \
                (const __attribute__((address_space(1))) void*)                \
                    (x + (size_t)(pbase + (s_ >> 3)) * DIM +                   \
                     (tt) * 32 + (s_ & 7) * 4),                                \
                (__attribute__((address_space(3))) void*)                      \
                    (&xs[bb][s_ * 4]),                                         \
                16, 0, 0);                                                     \
        }                                                                      \
    }

#define LOADX(sl, kq)                                                          \
    {                                                                          \
        _Pragma("unroll")                                                      \
        for (int i_ = 0; i_ < 8; ++i_)                                         \
            xv[sl][i_] = *(const float4*)(&xs[buf][(rr * 8 + i_) * 32 +        \
                                                   (kq) * 4]);                 \
    }

#define LOADC(sl, kq)                                                          \
    {                                                                          \
        _Pragma("unroll")                                                      \
        for (int j_ = 0; j_ < 4; ++j_)                                         \
            cv[sl][j_] = *(const float4*)(&cs[buf][((kq) * 4 + j_) * 64 +      \
                                                   c * 4]);                    \
    }

#define BODY_DIST(kq)                                                          \
    {                                                                          \
        if ((kq) < 7) { LOADX(((kq) + 1) & 1, (kq) + 1);                       \
                        LOADC(((kq) + 1) & 1, (kq) + 1); }                     \
        const float4 c0 = cv[(kq) & 1][0], c1 = cv[(kq) & 1][1];               \
        const float4 c2v = cv[(kq) & 1][2], c3 = cv[(kq) & 1][3];              \
        _Pragma("unroll")                                                      \
        for (int i = 0; i < 8; ++i) {                                          \
            const float4 xq = xv[(kq) & 1][i];                                 \
            float d0, d1, d2, d3;                                              \
            d0 = xq.x - c0.x;  acc[i][0] += d0 * d0;                           \
            d1 = xq.x - c0.y;  acc[i][1] += d1 * d1;                           \
            d2 = xq.x - c0.z;  acc[i][2] += d2 * d2;                           \
            d3 = xq.x - c0.w;  acc[i][3] += d3 * d3;                           \
            d0 = xq.y - c1.x;  acc[i][0] += d0 * d0;                           \
            d1 = xq.y - c1.y;  acc[i][1] += d1 * d1;                           \
            d2 = xq.y - c1.z;  acc[i][2] += d2 * d2;                           \
            d3 = xq.y - c1.w;  acc[i][3] += d3 * d3;                           \
            d0 = xq.z - c2v.x; acc[i][0] += d0 * d0;                           \
            d1 = xq.z - c2v.y; acc[i][1] += d1 * d1;                           \
            d2 = xq.z - c2v.z; acc[i][2] += d2 * d2;                           \
            d3 = xq.z - c2v.w; acc[i][3] += d3 * d3;                           \
            d0 = xq.w - c3.x;  acc[i][0] += d0 * d0;                           \
            d1 = xq.w - c3.y;  acc[i][1] += d1 * d1;                           \
            d2 = xq.w - c3.z;  acc[i][2] += d2 * d2;                           \
            d3 = xq.w - c3.w;  acc[i][3] += d3 * d3;                           \
        }                                                                      \
    }

__launch_bounds__(128)
__global__ void final_dist(const float* __restrict__ x,
                           const float* __restrict__ ct,
                           float* __restrict__ out) {
    __shared__ float xs[2][2048];
    __shared__ float cs[2][2048];

    const int tid = threadIdx.x;
    const int pbase = blockIdx.x * 64;
    const int rr = tid >> 4;
    const int c  = tid & 15;

    float4 xv[2][8];
    float4 cv[2][4];
    float acc[8][4] = {};

    DMA_T(0, 0);
    __syncthreads();

    int buf = 0;
    for (int t = 0; t < 16; ++t) {
        if (t < 15) DMA_T(t + 1, buf ^ 1);
        LOADX(0, 0); LOADC(0, 0);
        BODY_DIST(0); BODY_DIST(1); BODY_DIST(2); BODY_DIST(3);
        BODY_DIST(4); BODY_DIST(5); BODY_DIST(6); BODY_DIST(7);
        __syncthreads();
        buf ^= 1;
    }

    #pragma unroll
    for (int i = 0; i < 8; ++i) {
        int p = pbase + rr * 8 + i;
        float4 o;
        o.x = 1.0f / (sqrtf(acc[i][0]) + EPS_F);
        o.y = 1.0f / (sqrtf(acc[i][1]) + EPS_F);
        o.z = 1.0f / (sqrtf(acc[i][2]) + EPS_F);
        o.w = 1.0f / (sqrtf(acc[i][3]) + EPS_F);
        *(float4*)(out + (size_t)p * K_CL + c * 4) = o;
    }
}

extern "C" void kernel_launch(void* const* d_in, const int* in_sizes, int n_in,
                              void* d_out, int out_size, void* d_ws, size_t ws_size,
                              hipStream_t stream) {
    (void)in_sizes; (void)n_in; (void)out_size; (void)ws_size;
    const float* x = (const float*)d_in[0];
    float* ws      = (float*)d_ws;
    float* ct      = ws;
    float* sums    = ws + 32768;
    float* c2      = ws + 65536;
    unsigned short* cth = (unsigned short*)(ws + 65600);
    unsigned short* ctl = (unsigned short*)(ws + 81984);
    int*   rcnt    = (int*)(ws + 98368);
    int*   assignv = (int*)(ws + 98880);
    int*   lists   = (int*)d_out;
    float* out     = (float*)d_out;

    init_centers<<<64, 256, 0, stream>>>(x, ct, c2, cth, ctl);
    for (int it = 0; it < ITERS; ++it) {
        assign_mfma<<<2048, 64, 0, stream>>>(x, cth, ctl, c2, assignv);
        build_lists<<<dim3(64, 8), 64, 0, stream>>>(assignv, lists, rcnt);
        gather_det<<<dim3(64, 4), 128, 0, stream>>>(x, lists, rcnt, sums);
        update_centers<<<64, 256, 0, stream>>>(ct, sums, rcnt, c2, cth, ctl);
    }
    final_dist<<<512, 128, 0, stream>>>(x, ct, out);
}

// Round 9
// 879.724 us; speedup vs baseline: 3.5865x; 1.8733x over previous
//
#include <hip/hip_runtime.h>
#include <math.h>

#define N_PTS 32768
#define DIM   512
#define K_CL  64
#define ITERS 10
#define EPS_F 1e-8f

typedef __attribute__((ext_vector_type(8))) short          short8v;
typedef __attribute__((ext_vector_type(8))) unsigned short ushort8v;
typedef __attribute__((ext_vector_type(4))) float          f32x4v;

__device__ __forceinline__ unsigned short f2bf(float f) {
    unsigned u = __builtin_bit_cast(unsigned, f);
    unsigned r = u + 0x7fffu + ((u >> 16) & 1u);
    return (unsigned short)(r >> 16);
}
__device__ __forceinline__ float bf2f(unsigned short h) {
    return __builtin_bit_cast(float, ((unsigned)h) << 16);
}

// ws layout (floats):
//   ct:      [0, 32768)       fp32 centers transposed ct[d*64+k] (final_dist)
//   (spare): [32768, 65536)
//   c2:      [65536, 65600)
//   cth:     ushort @ float 65600  (64x512 bf16-hi, row-major)
//   ctl:     ushort @ float 81984  (64x512 bf16-lo)
//   rcnt:    int    @ float 98368  (64 clusters x 8 regions)
//   assignv: int    @ float 98880  (32768)
//   part:    float  @ 131648       (64 x 8 x 512 region partial sums)
// d_out holds per-cluster region lists during iterations:
//   lists[k*32768 + pc*4096 + i], region pc covers points [pc*4096,(pc+1)*4096)

__global__ void init_centers(const float* __restrict__ x,
                             float* __restrict__ ct,
                             float* __restrict__ c2,
                             unsigned short* __restrict__ cth,
                             unsigned short* __restrict__ ctl) {
    int k = blockIdx.x;
    int t = threadIdx.x;
    float ssum = 0.f;
    for (int d = t; d < DIM; d += 256) {
        float v = x[k * DIM + d];
        ct[d * K_CL + k] = v;
        unsigned short h = f2bf(v);
        cth[k * DIM + d] = h;
        ctl[k * DIM + d] = f2bf(v - bf2f(h));
        ssum += v * v;
    }
    #pragma unroll
    for (int off = 32; off; off >>= 1) ssum += __shfl_down(ssum, off);
    __shared__ float red[4];
    if ((t & 63) == 0) red[t >> 6] = ssum;
    __syncthreads();
    if (t == 0) c2[k] = red[0] + red[1] + red[2] + red[3];
}

// ---------------------------------------------------------------------------
// MFMA assignment, one wave per 16 points. dot = xh*ch + xh*cl + xl*ch
// (bf16 split; per-point MFMA sequence bitwise-identical to rounds 6/8).
// Writes assign[p] only — NO atomics, fully deterministic.
// ---------------------------------------------------------------------------
__launch_bounds__(64)
__global__ void assign_mfma(const float* __restrict__ x,
                            const unsigned short* __restrict__ cth,
                            const unsigned short* __restrict__ ctl,
                            const float* __restrict__ c2,
                            int* __restrict__ assignv) {
    const int lane  = threadIdx.x;
    const int mbase = blockIdx.x * 16;
    const int mrow  = lane & 15;
    const int kgrp  = lane >> 4;

    const float* xr = x + (size_t)(mbase + mrow) * DIM + kgrp * 8;
    const unsigned short* cbh = cth + (size_t)mrow * DIM + kgrp * 8;
    const unsigned short* cbl = ctl + (size_t)mrow * DIM + kgrp * 8;

    f32x4v acc[4];
    acc[0] = acc[1] = acc[2] = acc[3] = (f32x4v){0.f, 0.f, 0.f, 0.f};

    float4 xraw[2][2];
    xraw[0][0] = *(const float4*)(xr);
    xraw[0][1] = *(const float4*)(xr + 4);

    int buf = 0;
    for (int ks = 0; ks < 16; ++ks) {
        if (ks < 15) {
            xraw[buf ^ 1][0] = *(const float4*)(xr + (ks + 1) * 32);
            xraw[buf ^ 1][1] = *(const float4*)(xr + (ks + 1) * 32 + 4);
        }
        short8v bh[4], bl[4];
        #pragma unroll
        for (int nt = 0; nt < 4; ++nt) {
            const size_t off = (size_t)nt * 16 * DIM + ks * 32;
            bh[nt] = *(const short8v*)(cbh + off);
            bl[nt] = *(const short8v*)(cbl + off);
        }
        short8v ah, al;
        {
            float fs[8] = {xraw[buf][0].x, xraw[buf][0].y,
                           xraw[buf][0].z, xraw[buf][0].w,
                           xraw[buf][1].x, xraw[buf][1].y,
                           xraw[buf][1].z, xraw[buf][1].w};
            ushort8v h, l;
            #pragma unroll
            for (int i = 0; i < 8; ++i) {
                unsigned short hh = f2bf(fs[i]);
                h[i] = hh;
                l[i] = f2bf(fs[i] - bf2f(hh));
            }
            ah = __builtin_bit_cast(short8v, h);
            al = __builtin_bit_cast(short8v, l);
        }
        #pragma unroll
        for (int nt = 0; nt < 4; ++nt) {
            acc[nt] = __builtin_amdgcn_mfma_f32_16x16x32_bf16(
                ah, bh[nt], acc[nt], 0, 0, 0);
            acc[nt] = __builtin_amdgcn_mfma_f32_16x16x32_bf16(
                ah, bl[nt], acc[nt], 0, 0, 0);
            acc[nt] = __builtin_amdgcn_mfma_f32_16x16x32_bf16(
                al, bh[nt], acc[nt], 0, 0, 0);
        }
        buf ^= 1;
    }

    float c2v[4];
    #pragma unroll
    for (int nt = 0; nt < 4; ++nt) c2v[nt] = c2[nt * 16 + mrow];

    #pragma unroll
    for (int r = 0; r < 4; ++r) {
        float bv = 1e30f; int bc = 0;
        #pragma unroll
        for (int nt = 0; nt < 4; ++nt) {
            float v = c2v[nt] - 2.0f * acc[nt][r];
            if (v < bv) { bv = v; bc = nt * 16 + mrow; }
        }
        #pragma unroll
        for (int m = 1; m < 16; m <<= 1) {
            float ov = __shfl_xor(bv, m);
            int   oc = __shfl_xor(bc, m);
            if (ov < bv || (ov == bv && oc < bc)) { bv = ov; bc = oc; }
        }
        if (mrow == 0) assignv[mbase + kgrp * 4 + r] = bc;
    }
}

// Ordered wave-ballot compaction: cluster k, region pc (4096 points) ->
// members in strictly ascending point order. Fully deterministic.
__launch_bounds__(64)
__global__ void build_lists(const int* __restrict__ assignv,
                            int* __restrict__ lists,
                            int* __restrict__ rcnt) {
    const int k    = blockIdx.x;
    const int pc   = blockIdx.y;
    const int lane = threadIdx.x;
    const int p0   = pc * 4096;
    int* dst = lists + k * N_PTS + pc * 4096;

    int base = 0;
    int a_cur = assignv[p0 + lane];
    for (int it = 0; it < 64; ++it) {
        int a_nxt = 0;
        if (it < 63) a_nxt = assignv[p0 + (it + 1) * 64 + lane];
        bool pred = (a_cur == k);
        unsigned long long mask = __ballot(pred);
        int myoff = __popcll(mask & ((1ull << lane) - 1ull));
        if (pred) dst[base + myoff] = p0 + it * 64 + lane;
        base += __popcll(mask);
        a_cur = a_nxt;
    }
    if (lane == 0) rcnt[k * 8 + pc] = base;
}

// Deterministic region-parallel gather: one block per (cluster, region),
// 512 threads = all dims; members in ascending list order. No atomics.
__launch_bounds__(512)
__global__ void gather_part(const float* __restrict__ x,
                            const int* __restrict__ lists,
                            const int* __restrict__ rcnt,
                            float* __restrict__ part) {
    const int k  = blockIdx.x;
    const int pc = blockIdx.y;
    const int t  = threadIdx.x;   // dim 0..511
    const int n  = rcnt[k * 8 + pc];
    const int* lst = lists + k * N_PTS + pc * 4096;
    float acc = 0.f;
    int s = 0;
    for (; s + 8 <= n; s += 8) {
        int idx[8];
        #pragma unroll
        for (int q = 0; q < 8; ++q) idx[q] = lst[s + q];
        #pragma unroll
        for (int q = 0; q < 8; ++q) acc += x[(size_t)idx[q] * DIM + t];
    }
    for (; s < n; ++s) acc += x[(size_t)lst[s] * DIM + t];
    part[((size_t)k * 8 + pc) * DIM + t] = acc;
}

// Combine region partials in fixed ascending pc order (deterministic),
// divide, refresh fp32/bf16-split centers and c2.
__global__ void update_centers(float* __restrict__ ct,
                               const float* __restrict__ part,
                               const int* __restrict__ rcnt,
                               float* __restrict__ c2,
                               unsigned short* __restrict__ cth,
                               unsigned short* __restrict__ ctl) {
    int k = blockIdx.x;
    int t = threadIdx.x;
    int cnt = 0;
    #pragma unroll
    for (int pc = 0; pc < 8; ++pc) cnt += rcnt[k * 8 + pc];
    float fc = (float)cnt;
    float ssum = 0.f;
    for (int d = t; d < DIM; d += 256) {
        float v = ct[d * K_CL + k];
        if (cnt > 0) {
            float s = 0.f;
            #pragma unroll
            for (int pc = 0; pc < 8; ++pc)
                s += part[((size_t)k * 8 + pc) * DIM + d];
            v = s / fc;
        }
        ct[d * K_CL + k] = v;
        unsigned short h = f2bf(v);
        cth[k * DIM + d] = h;
        ctl[k * DIM + d] = f2bf(v - bf2f(h));
        ssum += v * v;
    }
    #pragma unroll
    for (int off = 32; off; off >>= 1) ssum += __shfl_down(ssum, off);
    __shared__ float red[4];
    if ((t & 63) == 0) red[t >> 6] = ssum;
    __syncthreads();
    if (t == 0) c2[k] = red[0] + red[1] + red[2] + red[3];
}

// ---------------------------------------------------------------------------
// Final distances via exact fp32 differencing (known-pass):
// d2 == 0 bitwise at any point equal to its center -> exact 1e8 entries.
// ---------------------------------------------------------------------------
#define DMA_T(tt, bb)                                                          \
    {                                                                          \
        _Pragma("unroll")                                                      \
        for (int q_ = 0; q_ < 4; ++q_) {                                       \
            __builtin_amdgcn_global_load_lds(                                  \
                (const __attribute__((address_space(1))) void*)                \
                    (ct + (tt) * 2048 + q_ * 512 + tid * 4),                   \
                (__attribute__((address_space(3))) void*)                      \
                    (&cs[bb][q_ * 512 + tid * 4]),                             \
                16, 0, 0);                                                     \
        }                                                                      \
        _Pragma("unroll")                                                      \
        for (int q_ = 0; q_ < 4; ++q_) {                                       \
            const int s_ = q_ * 128 + tid;                                     \
            __builtin_amdgcn_global_load_lds(                                  \
                (const __attribute__((address_space(1))) void*)                \
                    (x + (size_t)(pbase + (s_ >> 3)) * DIM +                   \
                     (tt) * 32 + (s_ & 7) * 4),                                \
                (__attribute__((address_space(3))) void*)                      \
                    (&xs[bb][s_ * 4]),                                         \
                16, 0, 0);                                                     \
        }                                                                      \
    }

#define LOADX(sl, kq)                                                          \
    {                                                                          \
        _Pragma("unroll")                                                      \
        for (int i_ = 0; i_ < 8; ++i_)                                         \
            xv[sl][i_] = *(const float4*)(&xs[buf][(rr * 8 + i_) * 32 +        \
                                                   (kq) * 4]);                 \
    }

#define LOADC(sl, kq)                                                          \
    {                                                                          \
        _Pragma("unroll")                                                      \
        for (int j_ = 0; j_ < 4; ++j_)                                         \
            cv[sl][j_] = *(const float4*)(&cs[buf][((kq) * 4 + j_) * 64 +      \
                                                   c * 4]);                    \
    }

#define BODY_DIST(kq)                                                          \
    {                                                                          \
        if ((kq) < 7) { LOADX(((kq) + 1) & 1, (kq) + 1);                       \
                        LOADC(((kq) + 1) & 1, (kq) + 1); }                     \
        const float4 c0 = cv[(kq) & 1][0], c1 = cv[(kq) & 1][1];               \
        const float4 c2v = cv[(kq) & 1][2], c3 = cv[(kq) & 1][3];              \
        _Pragma("unroll")                                                      \
        for (int i = 0; i < 8; ++i) {                                          \
            const float4 xq = xv[(kq) & 1][i];                                 \
            float d0, d1, d2, d3;                                              \
            d0 = xq.x - c0.x;  acc[i][0] += d0 * d0;                           \
            d1 = xq.x - c0.y;  acc[i][1] += d1 * d1;                           \
            d2 = xq.x - c0.z;  acc[i][2] += d2 * d2;                           \
            d3 = xq.x - c0.w;  acc[i][3] += d3 * d3;                           \
            d0 = xq.y - c1.x;  acc[i][0] += d0 * d0;                           \
            d1 = xq.y - c1.y;  acc[i][1] += d1 * d1;                           \
            d2 = xq.y - c1.z;  acc[i][2] += d2 * d2;                           \
            d3 = xq.y - c1.w;  acc[i][3] += d3 * d3;                           \
            d0 = xq.z - c2v.x; acc[i][0] += d0 * d0;                           \
            d1 = xq.z - c2v.y; acc[i][1] += d1 * d1;                           \
            d2 = xq.z - c2v.z; acc[i][2] += d2 * d2;                           \
            d3 = xq.z - c2v.w; acc[i][3] += d3 * d3;                           \
            d0 = xq.w - c3.x;  acc[i][0] += d0 * d0;                           \
            d1 = xq.w - c3.y;  acc[i][1] += d1 * d1;                           \
            d2 = xq.w - c3.z;  acc[i][2] += d2 * d2;                           \
            d3 = xq.w - c3.w;  acc[i][3] += d3 * d3;                           \
        }                                                                      \
    }

__launch_bounds__(128)
__global__ void final_dist(const float* __restrict__ x,
                           const float* __restrict__ ct,
                           float* __restrict__ out) {
    __shared__ float xs[2][2048];
    __shared__ float cs[2][2048];

    const int tid = threadIdx.x;
    const int pbase = blockIdx.x * 64;
    const int rr = tid >> 4;
    const int c  = tid & 15;

    float4 xv[2][8];
    float4 cv[2][4];
    float acc[8][4] = {};

    DMA_T(0, 0);
    __syncthreads();

    int buf = 0;
    for (int t = 0; t < 16; ++t) {
        if (t < 15) DMA_T(t + 1, buf ^ 1);
        LOADX(0, 0); LOADC(0, 0);
        BODY_DIST(0); BODY_DIST(1); BODY_DIST(2); BODY_DIST(3);
        BODY_DIST(4); BODY_DIST(5); BODY_DIST(6); BODY_DIST(7);
        __syncthreads();
        buf ^= 1;
    }

    #pragma unroll
    for (int i = 0; i < 8; ++i) {
        int p = pbase + rr * 8 + i;
        float4 o;
        o.x = 1.0f / (sqrtf(acc[i][0]) + EPS_F);
        o.y = 1.0f / (sqrtf(acc[i][1]) + EPS_F);
        o.z = 1.0f / (sqrtf(acc[i][2]) + EPS_F);
        o.w = 1.0f / (sqrtf(acc[i][3]) + EPS_F);
        *(float4*)(out + (size_t)p * K_CL + c * 4) = o;
    }
}

extern "C" void kernel_launch(void* const* d_in, const int* in_sizes, int n_in,
                              void* d_out, int out_size, void* d_ws, size_t ws_size,
                              hipStream_t stream) {
    (void)in_sizes; (void)n_in; (void)out_size; (void)ws_size;
    const float* x = (const float*)d_in[0];
    float* ws      = (float*)d_ws;
    float* ct      = ws;
    float* c2      = ws + 65536;
    unsigned short* cth = (unsigned short*)(ws + 65600);
    unsigned short* ctl = (unsigned short*)(ws + 81984);
    int*   rcnt    = (int*)(ws + 98368);
    int*   assignv = (int*)(ws + 98880);
    float* part    = ws + 131648;
    int*   lists   = (int*)d_out;
    float* out     = (float*)d_out;

    init_centers<<<64, 256, 0, stream>>>(x, ct, c2, cth, ctl);
    for (int it = 0; it < ITERS; ++it) {
        assign_mfma<<<2048, 64, 0, stream>>>(x, cth, ctl, c2, assignv);
        build_lists<<<dim3(64, 8), 64, 0, stream>>>(assignv, lists, rcnt);
        gather_part<<<dim3(64, 8), 512, 0, stream>>>(x, lists, rcnt, part);
        update_centers<<<64, 256, 0, stream>>>(ct, part, rcnt, c2, cth, ctl);
    }
    final_dist<<<512, 128, 0, stream>>>(x, ct, out);
}